// Round 6
// baseline (407.954 us; speedup 1.0000x reference)
//
#include <hip/hip_runtime.h>
#include <hip/hip_bf16.h>

// Problem constants
#define B_   4
#define S_   2048
#define H_   16
#define HD_  64
#define D_   1024
#define M_   (B_ * S_)   // 8192 rows

typedef unsigned short u16;
typedef __bf16 bf16x8 __attribute__((ext_vector_type(8)));
typedef float  f32x4  __attribute__((ext_vector_type(4)));
typedef unsigned short u16x8 __attribute__((ext_vector_type(8)));
typedef unsigned short u16x4 __attribute__((ext_vector_type(4)));

__device__ __forceinline__ float b2f(u16 u) {
    unsigned int x = ((unsigned int)u) << 16;
    return __builtin_bit_cast(float, x);
}
__device__ __forceinline__ u16 f2b(float f) {          // RNE
    unsigned int x = __builtin_bit_cast(unsigned int, f);
    x += 0x7fffu + ((x >> 16) & 1u);
    return (u16)(x >> 16);
}
__device__ __forceinline__ u16 f2bt(float f) {         // truncate (for P>=0)
    return (u16)(__builtin_bit_cast(unsigned int, f) >> 16);
}

// async global->LDS, 16B per lane; LDS dest = wave-uniform base + lane*16
typedef const __attribute__((address_space(1))) unsigned int* gas_u32p;
typedef __attribute__((address_space(3))) unsigned int* las_u32p;
__device__ __forceinline__ void gl_lds16(const u16* g, u16* lds_base) {
    __builtin_amdgcn_global_load_lds((gas_u32p)g, (las_u32p)lds_base, 16, 0, 0);
}

// ---------------------------------------------------------------------------
// x fp32 -> bf16, flat
// ---------------------------------------------------------------------------
__global__ __launch_bounds__(256) void cvt_k(const float* __restrict__ in,
                                             u16* __restrict__ out) {
    size_t i = ((size_t)blockIdx.x * 256 + threadIdx.x) * 8;
    float4 a = *(const float4*)(in + i);
    float4 b = *(const float4*)(in + i + 4);
    *(u16x8*)(out + i) = u16x8{f2b(a.x), f2b(a.y), f2b(a.z), f2b(a.w),
                               f2b(b.x), f2b(b.y), f2b(b.z), f2b(b.w)};
}

// ---------------------------------------------------------------------------
// Weight transpose + downcast + scale: fp32 [R][C] -> bf16 [C][R] * scale
// ---------------------------------------------------------------------------
__global__ __launch_bounds__(256) void transpose_k(const float* __restrict__ in,
                                                   u16* __restrict__ out,
                                                   int R, int C, float scale) {
    __shared__ u16 t[32][33];
    const int x0 = blockIdx.x * 32, y0 = blockIdx.y * 32;
    const int tx = threadIdx.x, ty = threadIdx.y;  // 32 x 8
#pragma unroll
    for (int i = 0; i < 32; i += 8)
        t[ty + i][tx] = f2b(in[(size_t)(y0 + ty + i) * C + x0 + tx] * scale);
    __syncthreads();
#pragma unroll
    for (int i = 0; i < 32; i += 8)
        out[(size_t)(x0 + ty + i) * R + y0 + tx] = t[tx][ty + i];
}

// ---------------------------------------------------------------------------
// GEMM (m97 structure): C[M,N] = A[M,K] @ W[K,N] + bias*bscale.
// A bf16 [M,K], Bt = W^T bf16 [N,K]. global_load_lds width-16 staging,
// LDS row stride = BK (required by the lane*16B dest mapping; b128 frag
// reads at 64B row stride are bank-uniform). Grid (M/BM, N/BN) so
// XCD = m-block % 8 -> per-XCD L2 holds its A-slice + all of W.
// OUT_MODE: 0 = bf16 [M,N], 1 = fp32 [M,N], 2 = bf16 Vt layout [B,H,HD,S].
// ---------------------------------------------------------------------------
#define BM 128
#define BN 128
#define BK 32

template <int OUT_MODE>
__global__ __launch_bounds__(256) void gemm_bias_k(
    const u16* __restrict__ A, const u16* __restrict__ Bt,
    const float* __restrict__ bias, float bscale, void* __restrict__ Cv,
    int M, int N, int K)
{
    __shared__ u16 As[BM * BK];
    __shared__ u16 Bs[BN * BK];

    const int tid  = threadIdx.x;
    const int lane = tid & 63;
    const int wave = tid >> 6;
    const int wr = wave >> 1, wc = wave & 1;
    const int l15 = lane & 15, quad = lane >> 4;
    const int m0 = blockIdx.x * BM, n0 = blockIdx.y * BN;

    const int srow = wave * 32 + (lane >> 2);   // + i*16
    const int skk  = (lane & 3) * 8;

    f32x4 acc[4][4] = {};

    for (int k0 = 0; k0 < K; k0 += BK) {
#pragma unroll
        for (int i = 0; i < 2; ++i) {
            const int r = srow + i * 16;
            gl_lds16(A  + (size_t)(m0 + r) * K + k0 + skk,
                     As + (wave * 32 + i * 16) * BK);
            gl_lds16(Bt + (size_t)(n0 + r) * K + k0 + skk,
                     Bs + (wave * 32 + i * 16) * BK);
        }
        __syncthreads();
        bf16x8 af[4], bfr[4];
#pragma unroll
        for (int t = 0; t < 4; ++t) {
            af[t]  = *(const bf16x8*)(As + (wr * 64 + t * 16 + l15) * BK + quad * 8);
            bfr[t] = *(const bf16x8*)(Bs + (wc * 64 + t * 16 + l15) * BK + quad * 8);
        }
#pragma unroll
        for (int mt = 0; mt < 4; ++mt)
#pragma unroll
            for (int nt = 0; nt < 4; ++nt)
                acc[mt][nt] = __builtin_amdgcn_mfma_f32_16x16x32_bf16(
                    af[mt], bfr[nt], acc[mt][nt], 0, 0, 0);
        __syncthreads();
    }

#pragma unroll
    for (int nt = 0; nt < 4; ++nt) {
        int col = n0 + wc * 64 + nt * 16 + l15;
        float bv = bias[col] * bscale;
#pragma unroll
        for (int mt = 0; mt < 4; ++mt) {
            int rbase = m0 + wr * 64 + mt * 16 + quad * 4;
            if constexpr (OUT_MODE == 2) {
                int bidx = rbase >> 11, s = rbase & (S_ - 1);
                int hh = col >> 6, hd = col & 63;
                u16* C = (u16*)Cv;
                u16x4 pk{f2b(acc[mt][nt][0] + bv), f2b(acc[mt][nt][1] + bv),
                         f2b(acc[mt][nt][2] + bv), f2b(acc[mt][nt][3] + bv)};
                *(u16x4*)(C + (((size_t)(bidx * H_ + hh)) * HD_ + hd) * S_ + s) = pk;
            } else {
#pragma unroll
                for (int r2 = 0; r2 < 4; ++r2) {
                    float v = acc[mt][nt][r2] + bv;
                    if constexpr (OUT_MODE == 0)
                        ((u16*)Cv)[(size_t)(rbase + r2) * N + col] = f2b(v);
                    else
                        ((float*)Cv)[(size_t)(rbase + r2) * N + col] = v;
                }
            }
        }
    }
}

// ---------------------------------------------------------------------------
// Causal flash attention, MFMA, no barriers. Q pre-scaled by log2(e)/8.
// K [B,S,H,HD], Vt [B,H,HD,S]. Block = q-tile pair {j, 31-j} of one (b,h):
// 33 compute-passes per block (balanced), grid (bh, j) so all 16 j-blocks
// of a head share one XCD (8 heads x 512KB K/V = 4MB = one L2).
// 4 waves split each q-tile (16 rows). K/V frags are 16B global reads held
// in regs. Softmax: p = exp2(s) directly (|s| small), l reduced at the end.
// Mask VALU only on the diagonal tile. P C->B layout via per-wave swizzled
// LDS scratch.
// ---------------------------------------------------------------------------
__global__ __launch_bounds__(256) void attn_mfma_k(
    const u16* __restrict__ Qm, const u16* __restrict__ Km,
    const u16* __restrict__ Vtg, u16* __restrict__ Om)
{
    __shared__ u16 Ps[4][16 * 64];

    const int tid  = threadIdx.x;
    const int lane = tid & 63;
    const int wave = tid >> 6;
    const int l15  = lane & 15;
    const int quad = lane >> 4;
    const int bh = blockIdx.x, b = bh >> 4, h = bh & (H_ - 1);
    const int j  = blockIdx.y;             // 0..15
    const int dg0 = j, dg1 = 31 - j;

    const u16* Qg = Qm + (size_t)b * S_ * D_ + h * HD_;
    const u16* Kg = Km + (size_t)b * S_ * D_ + h * HD_;
    const u16* Vg = Vtg + ((size_t)(b * H_ + h)) * HD_ * S_;

    bf16x8 qf0[2], qf1[2];
    {
        const u16* qp = Qg + (size_t)(dg0 * 64 + wave * 16 + l15) * D_ + quad * 8;
        qf0[0] = *(const bf16x8*)qp; qf0[1] = *(const bf16x8*)(qp + 32);
        qp = Qg + (size_t)(dg1 * 64 + wave * 16 + l15) * D_ + quad * 8;
        qf1[0] = *(const bf16x8*)qp; qf1[1] = *(const bf16x8*)(qp + 32);
    }

    f32x4 of0[4] = {}, of1[4] = {};
    float lacc0 = 0.f, lacc1 = 0.f;
    u16* pw = Ps[wave];
    const int qloc = wave * 16 + l15;

    bf16x8 kf[4][2], vf[4][2];

    auto pass = [&](const bf16x8 (&qf)[2], f32x4 (&of)[4], float& lacc,
                    bool domask) {
        f32x4 sf[4];
#pragma unroll
        for (int kt = 0; kt < 4; ++kt) {
            f32x4 a = {};
            a = __builtin_amdgcn_mfma_f32_16x16x32_bf16(kf[kt][0], qf[0], a, 0, 0, 0);
            a = __builtin_amdgcn_mfma_f32_16x16x32_bf16(kf[kt][1], qf[1], a, 0, 0, 0);
            sf[kt] = a;
        }
        float ls = 0.f;
        u16 pb[16];
        if (domask) {
#pragma unroll
            for (int kt = 0; kt < 4; ++kt)
#pragma unroll
                for (int r = 0; r < 4; ++r) {
                    float v = sf[kt][r];
                    if (kt * 16 + quad * 4 + r > qloc) v = -INFINITY;
                    float p = __builtin_amdgcn_exp2f(v);
                    ls += p; pb[kt * 4 + r] = f2bt(p);
                }
        } else {
#pragma unroll
            for (int kt = 0; kt < 4; ++kt)
#pragma unroll
                for (int r = 0; r < 4; ++r) {
                    float p = __builtin_amdgcn_exp2f(sf[kt][r]);
                    ls += p; pb[kt * 4 + r] = f2bt(p);
                }
        }
        lacc += ls;
#pragma unroll
        for (int kt = 0; kt < 4; ++kt) {
            const int g = kt * 16 + quad * 4;
            const int pos = ((g >> 3) ^ (l15 & 7)) * 8 + (g & 7);
            *(u16x4*)(pw + l15 * 64 + pos) =
                u16x4{pb[kt * 4], pb[kt * 4 + 1], pb[kt * 4 + 2], pb[kt * 4 + 3]};
        }
        bf16x8 pf0 = *(const bf16x8*)(pw + l15 * 64 + ((quad    ) ^ (l15 & 7)) * 8);
        bf16x8 pf1 = *(const bf16x8*)(pw + l15 * 64 + ((quad + 4) ^ (l15 & 7)) * 8);
#pragma unroll
        for (int dt = 0; dt < 4; ++dt) {
            of[dt] = __builtin_amdgcn_mfma_f32_16x16x32_bf16(vf[dt][0], pf0, of[dt], 0, 0, 0);
            of[dt] = __builtin_amdgcn_mfma_f32_16x16x32_bf16(vf[dt][1], pf1, of[dt], 0, 0, 0);
        }
    };

    const int T = 32 - j;
    for (int t = 0; t < T; ++t) {
#pragma unroll
        for (int kt = 0; kt < 4; ++kt) {
            const u16* kp = Kg + (size_t)(t * 64 + kt * 16 + l15) * D_ + quad * 8;
            kf[kt][0] = *(const bf16x8*)kp;
            kf[kt][1] = *(const bf16x8*)(kp + 32);
        }
#pragma unroll
        for (int dt = 0; dt < 4; ++dt) {
            const u16* vp = Vg + (size_t)(dt * 16 + l15) * S_ + t * 64 + quad * 8;
            vf[dt][0] = *(const bf16x8*)vp;
            vf[dt][1] = *(const bf16x8*)(vp + 32);
        }
        if (t < dg0) {
            pass(qf0, of0, lacc0, false);
            pass(qf1, of1, lacc1, false);
        } else if (t == dg0) {
            pass(qf0, of0, lacc0, true);
            pass(qf1, of1, lacc1, false);
        } else if (t < dg1) {
            pass(qf1, of1, lacc1, false);
        } else {
            pass(qf1, of1, lacc1, true);
        }
    }

    auto epi = [&](const f32x4 (&of)[4], float lacc, int dgq) {
        float ls = lacc;
        ls += __shfl_xor(ls, 16);
        ls += __shfl_xor(ls, 32);
        const float inv = 1.f / ls;
#pragma unroll
        for (int dt = 0; dt < 4; ++dt) {
            const int g = dt * 16 + quad * 4;
            const int pos = ((g >> 3) ^ (l15 & 7)) * 8 + (g & 7);
            *(u16x4*)(pw + l15 * 64 + pos) =
                u16x4{f2b(of[dt][0] * inv), f2b(of[dt][1] * inv),
                      f2b(of[dt][2] * inv), f2b(of[dt][3] * inv)};
        }
        const int r  = lane >> 2;
        const int cp = lane & 3;
        u16x8 o0 = *(const u16x8*)(pw + r * 64 + ((2 * cp    ) ^ (r & 7)) * 8);
        u16x8 o1 = *(const u16x8*)(pw + r * 64 + ((2 * cp + 1) ^ (r & 7)) * 8);
        u16* op = Om + ((size_t)(b * S_ + dgq * 64 + wave * 16 + r)) * D_ + h * 64 + cp * 16;
        *(u16x8*)op = o0;
        *(u16x8*)(op + 8) = o1;
    };
    epi(of0, lacc0, dg0);
    epi(of1, lacc1, dg1);
}

// ---------------------------------------------------------------------------
extern "C" void kernel_launch(void* const* d_in, const int* in_sizes, int n_in,
                              void* d_out, int out_size, void* d_ws, size_t ws_size,
                              hipStream_t stream)
{
    (void)in_sizes; (void)n_in; (void)out_size; (void)ws_size;
    const float* x  = (const float*)d_in[0];
    const float* Wq = (const float*)d_in[1];
    const float* bq = (const float*)d_in[2];
    const float* Wk = (const float*)d_in[3];
    const float* bk = (const float*)d_in[4];
    const float* Wv = (const float*)d_in[5];
    const float* bv = (const float*)d_in[6];
    const float* Wo = (const float*)d_in[7];
    const float* bo = (const float*)d_in[8];

    const float cscale = 0.18033688011112042f;  // log2(e)/sqrt(64)

    u16* ws = (u16*)d_ws;
    const size_t MD = (size_t)M_ * D_;
    const size_t DD = (size_t)D_ * D_;
    u16* xb  = ws;            // bf16 [M, D]
    u16* Qb  = xb + MD;       // bf16 [B,S,H,HD], pre-scaled
    u16* Kb  = Qb + MD;       // bf16 [B,S,H,HD]
    u16* Vtb = Kb + MD;       // bf16 [B,H,HD,S]
    u16* Cb  = Vtb + MD;      // ctx bf16 [M, D]
    u16* WqT = Cb + MD;
    u16* WkT = WqT + DD;
    u16* WvT = WkT + DD;
    u16* WoT = WvT + DD;

    cvt_k<<<M_ * D_ / 2048, 256, 0, stream>>>(x, xb);

    dim3 tg(D_ / 32, D_ / 32), tb(32, 8);
    transpose_k<<<tg, tb, 0, stream>>>(Wq, WqT, D_, D_, cscale);
    transpose_k<<<tg, tb, 0, stream>>>(Wk, WkT, D_, D_, 1.0f);
    transpose_k<<<tg, tb, 0, stream>>>(Wv, WvT, D_, D_, 1.0f);
    transpose_k<<<tg, tb, 0, stream>>>(Wo, WoT, D_, D_, 1.0f);

    dim3 gg(M_ / BM, D_ / BN);  // (64, 8): XCD = m-block % 8
    gemm_bias_k<0><<<gg, 256, 0, stream>>>(xb, WqT, bq, cscale, Qb,  M_, D_, D_);
    gemm_bias_k<0><<<gg, 256, 0, stream>>>(xb, WkT, bk, 1.0f,   Kb,  M_, D_, D_);
    gemm_bias_k<2><<<gg, 256, 0, stream>>>(xb, WvT, bv, 1.0f,   Vtb, M_, D_, D_);

    attn_mfma_k<<<dim3(B_ * H_, 16), 256, 0, stream>>>(Qb, Kb, Vtb, Cb);

    gemm_bias_k<1><<<gg, 256, 0, stream>>>(Cb, WoT, bo, 1.0f, d_out, M_, D_, D_);
}

// Round 7
// 290.980 us; speedup vs baseline: 1.4020x; 1.4020x over previous
//
#include <hip/hip_runtime.h>
#include <hip/hip_bf16.h>

// Problem constants
#define B_   4
#define S_   2048
#define H_   16
#define HD_  64
#define D_   1024
#define M_   (B_ * S_)   // 8192 rows
#define N3_  3072

typedef unsigned short u16;
typedef __bf16 bf16x8 __attribute__((ext_vector_type(8)));
typedef float  f32x4  __attribute__((ext_vector_type(4)));
typedef unsigned short u16x8 __attribute__((ext_vector_type(8)));
typedef unsigned short u16x4 __attribute__((ext_vector_type(4)));

__device__ __forceinline__ float b2f(u16 u) {
    unsigned int x = ((unsigned int)u) << 16;
    return __builtin_bit_cast(float, x);
}
__device__ __forceinline__ u16 f2b(float f) {          // RNE
    unsigned int x = __builtin_bit_cast(unsigned int, f);
    x += 0x7fffu + ((x >> 16) & 1u);
    return (u16)(x >> 16);
}
__device__ __forceinline__ u16 f2bt(float f) {         // truncate (for P>=0)
    return (u16)(__builtin_bit_cast(unsigned int, f) >> 16);
}

// async global->LDS, 16B/lane; LDS dest = wave-uniform base + lane*16
typedef const __attribute__((address_space(1))) unsigned int* gas_u32p;
typedef __attribute__((address_space(3))) unsigned int* las_u32p;
__device__ __forceinline__ void gl_lds16(const u16* g, u16* lds_base) {
    __builtin_amdgcn_global_load_lds((gas_u32p)g, (las_u32p)lds_base, 16, 0, 0);
}

// ---------------------------------------------------------------------------
// x fp32 -> bf16, flat
// ---------------------------------------------------------------------------
__global__ __launch_bounds__(256) void cvt_k(const float* __restrict__ in,
                                             u16* __restrict__ out) {
    size_t i = ((size_t)blockIdx.x * 256 + threadIdx.x) * 8;
    float4 a = *(const float4*)(in + i);
    float4 b = *(const float4*)(in + i + 4);
    *(u16x8*)(out + i) = u16x8{f2b(a.x), f2b(a.y), f2b(a.z), f2b(a.w),
                               f2b(b.x), f2b(b.y), f2b(b.z), f2b(b.w)};
}

// ---------------------------------------------------------------------------
// 4 weight transposes fused: z in {0,1,2}: Wq/Wk/Wv -> WqkvT sections
// (z=0 scaled by cscale); z=3: Wo -> WoT.
// ---------------------------------------------------------------------------
__global__ __launch_bounds__(256) void transpose4_k(
    const float* __restrict__ w0, const float* __restrict__ w1,
    const float* __restrict__ w2, const float* __restrict__ w3,
    u16* __restrict__ oqkv, u16* __restrict__ owo, float scale0) {
    __shared__ u16 t[32][33];
    const int z = blockIdx.z;
    const float* in = (z == 0) ? w0 : (z == 1) ? w1 : (z == 2) ? w2 : w3;
    u16* out = (z < 3) ? oqkv + (size_t)z * D_ * D_ : owo;
    const float sc = (z == 0) ? scale0 : 1.0f;
    const int x0 = blockIdx.x * 32, y0 = blockIdx.y * 32;
    const int tx = threadIdx.x & 31, ty = threadIdx.x >> 5;  // 32 x 8
#pragma unroll
    for (int i = 0; i < 32; i += 8)
        t[ty + i][tx] = f2b(in[(size_t)(y0 + ty + i) * D_ + x0 + tx] * sc);
    __syncthreads();
#pragma unroll
    for (int i = 0; i < 32; i += 8)
        out[(size_t)(x0 + ty + i) * D_ + y0 + tx] = t[tx][ty + i];
}

// ---------------------------------------------------------------------------
// GEMM core (m97 structure, BK=64, XOR-swizzled LDS): C = A @ W + bias.
// A bf16 [M,K], Bt = W^T bf16 [N,K]. global_load_lds width-16 staging into
// 128B rows; global-side chunk x r8 XOR makes b128 frag reads 2-way (free).
// MODE 0: fused QKV epilogue (N=3072; col>>10 -> Q bf16 / K bf16 / V->Vt).
// MODE 1: fp32 out [M,N].
// ---------------------------------------------------------------------------
#define BM 128
#define BN 128
#define BK 64

template <int MODE>
__global__ __launch_bounds__(256) void gemm_core(
    const u16* __restrict__ A, const u16* __restrict__ Bt,
    const float* __restrict__ b0, const float* __restrict__ b1,
    const float* __restrict__ b2, float cscale,
    void* __restrict__ O0, void* __restrict__ O1, void* __restrict__ O2,
    int M, int N, int K)
{
    __shared__ __align__(16) u16 As[BM * BK];   // 16 KB
    __shared__ __align__(16) u16 Bs[BN * BK];   // 16 KB

    const int tid  = threadIdx.x;
    const int lane = tid & 63;
    const int wave = tid >> 6;
    const int wr = wave >> 1, wc = wave & 1;
    const int l15 = lane & 15, quad = lane >> 4;
    const int m0 = blockIdx.x * BM, n0 = blockIdx.y * BN;
    const int r8 = lane >> 3;
    const int csw = ((lane & 7) ^ r8) * 8;      // swizzled global chunk

    f32x4 acc[4][4] = {};

    for (int k0 = 0; k0 < K; k0 += BK) {
#pragma unroll
        for (int i = 0; i < 4; ++i) {
            const int row = wave * 32 + i * 8 + r8;
            gl_lds16(A  + (size_t)(m0 + row) * K + k0 + csw,
                     As + (wave * 32 + i * 8) * BK);
            gl_lds16(Bt + (size_t)(n0 + row) * K + k0 + csw,
                     Bs + (wave * 32 + i * 8) * BK);
        }
        __syncthreads();
        bf16x8 af[4][2], bfr[4][2];
#pragma unroll
        for (int t = 0; t < 4; ++t) {
            const u16* ap = As + (wr * 64 + t * 16 + l15) * BK;
            const u16* bp = Bs + (wc * 64 + t * 16 + l15) * BK;
            const int s7 = l15 & 7;
            af[t][0]  = *(const bf16x8*)(ap + ((quad    ) ^ s7) * 8);
            af[t][1]  = *(const bf16x8*)(ap + ((quad + 4) ^ s7) * 8);
            bfr[t][0] = *(const bf16x8*)(bp + ((quad    ) ^ s7) * 8);
            bfr[t][1] = *(const bf16x8*)(bp + ((quad + 4) ^ s7) * 8);
        }
#pragma unroll
        for (int mt = 0; mt < 4; ++mt)
#pragma unroll
            for (int nt = 0; nt < 4; ++nt) {
                acc[mt][nt] = __builtin_amdgcn_mfma_f32_16x16x32_bf16(
                    af[mt][0], bfr[nt][0], acc[mt][nt], 0, 0, 0);
                acc[mt][nt] = __builtin_amdgcn_mfma_f32_16x16x32_bf16(
                    af[mt][1], bfr[nt][1], acc[mt][nt], 0, 0, 0);
            }
        __syncthreads();
    }

#pragma unroll
    for (int nt = 0; nt < 4; ++nt) {
        const int col = n0 + wc * 64 + nt * 16 + l15;
        if constexpr (MODE == 1) {
            const float bv = b0[col];
#pragma unroll
            for (int mt = 0; mt < 4; ++mt) {
                const int rbase = m0 + wr * 64 + mt * 16 + quad * 4;
#pragma unroll
                for (int r2 = 0; r2 < 4; ++r2)
                    ((float*)O0)[(size_t)(rbase + r2) * N + col] =
                        acc[mt][nt][r2] + bv;
            }
        } else {
            const int qidx = col >> 10, ncol = col & (D_ - 1);
            const float bv = (qidx == 0) ? b0[ncol] * cscale
                           : (qidx == 1) ? b1[ncol] : b2[ncol];
#pragma unroll
            for (int mt = 0; mt < 4; ++mt) {
                const int rbase = m0 + wr * 64 + mt * 16 + quad * 4;
                if (qidx == 2) {   // Vt layout [B][H][HD][S]
                    const int bidx = rbase >> 11, s = rbase & (S_ - 1);
                    const int hh = ncol >> 6, hd = ncol & 63;
                    u16x4 pk{f2b(acc[mt][nt][0] + bv), f2b(acc[mt][nt][1] + bv),
                             f2b(acc[mt][nt][2] + bv), f2b(acc[mt][nt][3] + bv)};
                    *(u16x4*)((u16*)O2 +
                        (((size_t)(bidx * H_ + hh)) * HD_ + hd) * S_ + s) = pk;
                } else {
                    u16* dst = (qidx == 0) ? (u16*)O0 : (u16*)O1;
#pragma unroll
                    for (int r2 = 0; r2 < 4; ++r2)
                        dst[(size_t)(rbase + r2) * D_ + ncol] =
                            f2b(acc[mt][nt][r2] + bv);
                }
            }
        }
    }
}

// ---------------------------------------------------------------------------
// Causal flash attention, MFMA, LDS-dbuf K/V staging (one copy per block).
// Q pre-scaled by log2(e)/8. K [B,S,H,HD], Vt [B,H,HD,S].
// Block = 4 q-tiles {j,15-j,16+j,31-j} of one (b,h): 66 passes/block,
// grid (bh, j=0..7) -> XCD = bh%8 (head-local L2). 4 waves split each
// q-tile (16 rows). K/V tiles: global_load_lds, double-buffered, prefetch
// issued one full iteration ahead (barrier vmcnt drain ~free). XOR swizzle
// on the global-side chunk makes all b128 LDS reads 2-way (free).
// Softmax: p = exp2(s) directly, l reduced at the end. Mask only diagonal.
// ---------------------------------------------------------------------------
__global__ __launch_bounds__(256) void attn_mfma_k(
    const u16* __restrict__ Qm, const u16* __restrict__ Km,
    const u16* __restrict__ Vtg, u16* __restrict__ Om)
{
    __shared__ __align__(16) u16 Kbuf[2][64 * 64];   // 16 KB
    __shared__ __align__(16) u16 Vbuf[2][64 * 64];   // 16 KB
    __shared__ __align__(16) u16 Ps[4][16 * 64];     //  8 KB

    const int tid  = threadIdx.x;
    const int lane = tid & 63;
    const int wave = tid >> 6;
    const int l15  = lane & 15;
    const int quad = lane >> 4;
    const int bh = blockIdx.x, b = bh >> 4, h = bh & (H_ - 1);
    const int j  = blockIdx.y;                 // 0..7
    const int dg[4] = { j, 15 - j, 16 + j, 31 - j };

    const u16* Qg = Qm + (size_t)b * S_ * D_ + h * HD_;
    const u16* Kg = Km + (size_t)b * S_ * D_ + h * HD_;
    const u16* Vg = Vtg + ((size_t)(b * H_ + h)) * HD_ * S_;

    bf16x8 qf[4][2];
#pragma unroll
    for (int qs = 0; qs < 4; ++qs) {
        const u16* qp = Qg + (size_t)(dg[qs] * 64 + wave * 16 + l15) * D_ + quad * 8;
        qf[qs][0] = *(const bf16x8*)qp;
        qf[qs][1] = *(const bf16x8*)(qp + 32);
    }

    f32x4 of[4][4] = {};
    float lacc[4] = {0.f, 0.f, 0.f, 0.f};
    u16* pw = Ps[wave];
    const int qloc = wave * 16 + l15;
    const int r8 = lane >> 3;
    const int csw = ((lane & 7) ^ r8) * 8;     // swizzled global chunk

    auto stage = [&](int t, int bsel) {
        u16* kb = Kbuf[bsel];
        u16* vb = Vbuf[bsel];
#pragma unroll
        for (int i = 0; i < 2; ++i) {
            const int row = wave * 16 + i * 8 + r8;
            gl_lds16(Kg + (size_t)(t * 64 + row) * D_ + csw,
                     kb + (wave * 16 + i * 8) * 64);
            gl_lds16(Vg + (size_t)row * S_ + t * 64 + csw,
                     vb + (wave * 16 + i * 8) * 64);
        }
    };

    bf16x8 kf[4][2], vf[4][2];

    auto pass = [&](const bf16x8 (&q)[2], f32x4 (&o)[4], float& la, bool domask) {
        f32x4 sf[4];
#pragma unroll
        for (int kt = 0; kt < 4; ++kt) {
            f32x4 a = {};
            a = __builtin_amdgcn_mfma_f32_16x16x32_bf16(kf[kt][0], q[0], a, 0, 0, 0);
            a = __builtin_amdgcn_mfma_f32_16x16x32_bf16(kf[kt][1], q[1], a, 0, 0, 0);
            sf[kt] = a;
        }
        float ls = 0.f;
        u16 pb[16];
        if (domask) {
#pragma unroll
            for (int kt = 0; kt < 4; ++kt)
#pragma unroll
                for (int r = 0; r < 4; ++r) {
                    float v = sf[kt][r];
                    if (kt * 16 + quad * 4 + r > qloc) v = -INFINITY;
                    float p = __builtin_amdgcn_exp2f(v);
                    ls += p; pb[kt * 4 + r] = f2bt(p);
                }
        } else {
#pragma unroll
            for (int kt = 0; kt < 4; ++kt)
#pragma unroll
                for (int r = 0; r < 4; ++r) {
                    float p = __builtin_amdgcn_exp2f(sf[kt][r]);
                    ls += p; pb[kt * 4 + r] = f2bt(p);
                }
        }
        la += ls;
#pragma unroll
        for (int kt = 0; kt < 4; ++kt) {
            const int g = kt * 16 + quad * 4;
            const int pos = ((g >> 3) ^ (l15 & 7)) * 8 + (g & 7);
            *(u16x4*)(pw + l15 * 64 + pos) =
                u16x4{pb[kt * 4], pb[kt * 4 + 1], pb[kt * 4 + 2], pb[kt * 4 + 3]};
        }
        bf16x8 pf0 = *(const bf16x8*)(pw + l15 * 64 + ((quad    ) ^ (l15 & 7)) * 8);
        bf16x8 pf1 = *(const bf16x8*)(pw + l15 * 64 + ((quad + 4) ^ (l15 & 7)) * 8);
#pragma unroll
        for (int dt = 0; dt < 4; ++dt) {
            o[dt] = __builtin_amdgcn_mfma_f32_16x16x32_bf16(vf[dt][0], pf0, o[dt], 0, 0, 0);
            o[dt] = __builtin_amdgcn_mfma_f32_16x16x32_bf16(vf[dt][1], pf1, o[dt], 0, 0, 0);
        }
    };

    const int T = 32 - j;
    stage(0, 0);
    for (int t = 0; t < T; ++t) {
        __syncthreads();                       // buf[t&1] ready (vmcnt drain)
        if (t + 1 < T) stage(t + 1, (t + 1) & 1);
        const u16* kb = Kbuf[t & 1];
        const u16* vb = Vbuf[t & 1];
#pragma unroll
        for (int kt = 0; kt < 4; ++kt) {
            const u16* kp = kb + (kt * 16 + l15) * 64;
            const u16* vp = vb + (kt * 16 + l15) * 64;
            const int s7 = l15 & 7;
            kf[kt][0] = *(const bf16x8*)(kp + ((quad    ) ^ s7) * 8);
            kf[kt][1] = *(const bf16x8*)(kp + ((quad + 4) ^ s7) * 8);
            vf[kt][0] = *(const bf16x8*)(vp + ((quad    ) ^ s7) * 8);
            vf[kt][1] = *(const bf16x8*)(vp + ((quad + 4) ^ s7) * 8);
        }
        if (t <= dg[0]) pass(qf[0], of[0], lacc[0], t == dg[0]);
        if (t <= dg[1]) pass(qf[1], of[1], lacc[1], t == dg[1]);
        if (t <= dg[2]) pass(qf[2], of[2], lacc[2], t == dg[2]);
        if (t <= dg[3]) pass(qf[3], of[3], lacc[3], t == dg[3]);
    }

    auto epi = [&](const f32x4 (&o)[4], float la, int dgq) {
        float ls = la;
        ls += __shfl_xor(ls, 16);
        ls += __shfl_xor(ls, 32);
        const float inv = 1.f / ls;
#pragma unroll
        for (int dt = 0; dt < 4; ++dt) {
            const int g = dt * 16 + quad * 4;
            const int pos = ((g >> 3) ^ (l15 & 7)) * 8 + (g & 7);
            *(u16x4*)(pw + l15 * 64 + pos) =
                u16x4{f2b(o[dt][0] * inv), f2b(o[dt][1] * inv),
                      f2b(o[dt][2] * inv), f2b(o[dt][3] * inv)};
        }
        const int r  = lane >> 2;
        const int cp = lane & 3;
        u16x8 o0 = *(const u16x8*)(pw + r * 64 + ((2 * cp    ) ^ (r & 7)) * 8);
        u16x8 o1 = *(const u16x8*)(pw + r * 64 + ((2 * cp + 1) ^ (r & 7)) * 8);
        u16* op = Om + ((size_t)(b * S_ + dgq * 64 + wave * 16 + r)) * D_ + h * 64 + cp * 16;
        *(u16x8*)op = o0;
        *(u16x8*)(op + 8) = o1;
    };
    epi(of[0], lacc[0], dg[0]);
    epi(of[1], lacc[1], dg[1]);
    epi(of[2], lacc[2], dg[2]);
    epi(of[3], lacc[3], dg[3]);
}

// ---------------------------------------------------------------------------
extern "C" void kernel_launch(void* const* d_in, const int* in_sizes, int n_in,
                              void* d_out, int out_size, void* d_ws, size_t ws_size,
                              hipStream_t stream)
{
    (void)in_sizes; (void)n_in; (void)out_size; (void)ws_size;
    const float* x  = (const float*)d_in[0];
    const float* Wq = (const float*)d_in[1];
    const float* bq = (const float*)d_in[2];
    const float* Wk = (const float*)d_in[3];
    const float* bk = (const float*)d_in[4];
    const float* Wv = (const float*)d_in[5];
    const float* bv = (const float*)d_in[6];
    const float* Wo = (const float*)d_in[7];
    const float* bo = (const float*)d_in[8];

    const float cscale = 0.18033688011112042f;  // log2(e)/sqrt(64)

    u16* ws = (u16*)d_ws;
    const size_t MD = (size_t)M_ * D_;
    const size_t DD = (size_t)D_ * D_;
    u16* xb    = ws;            // bf16 [M, D]
    u16* Qb    = xb + MD;       // bf16 [B,S,H,HD], pre-scaled
    u16* Kb    = Qb + MD;       // bf16 [B,S,H,HD]
    u16* Vtb   = Kb + MD;       // bf16 [B,H,HD,S]
    u16* Cb    = Vtb + MD;      // ctx bf16 [M, D]
    u16* WqkvT = Cb + MD;       // bf16 [3072, 1024] (Q section pre-scaled)
    u16* WoT   = WqkvT + 3 * DD;

    cvt_k<<<M_ * D_ / 2048, 256, 0, stream>>>(x, xb);

    transpose4_k<<<dim3(D_ / 32, D_ / 32, 4), 256, 0, stream>>>(
        Wq, Wk, Wv, Wo, WqkvT, WoT, cscale);

    gemm_core<0><<<dim3(M_ / BM, N3_ / BN), 256, 0, stream>>>(
        xb, WqkvT, bq, bk, bv, cscale, Qb, Kb, Vtb, M_, N3_, D_);

    attn_mfma_k<<<dim3(B_ * H_, 8), 256, 0, stream>>>(Qb, Kb, Vtb, Cb);

    gemm_core<1><<<dim3(M_ / BM, D_ / BN), 256, 0, stream>>>(
        Cb, WoT, bo, nullptr, nullptr, 1.0f, d_out, nullptr, nullptr, M_, D_, D_);
}

// Round 8
// 266.986 us; speedup vs baseline: 1.5280x; 1.0899x over previous
//
#include <hip/hip_runtime.h>
#include <hip/hip_bf16.h>

// Problem constants
#define B_   4
#define S_   2048
#define H_   16
#define HD_  64
#define D_   1024
#define M_   (B_ * S_)   // 8192 rows
#define N3_  3072

typedef unsigned short u16;
typedef __bf16 bf16x8 __attribute__((ext_vector_type(8)));
typedef float  f32x4  __attribute__((ext_vector_type(4)));
typedef int    i32x4  __attribute__((ext_vector_type(4)));
typedef unsigned short u16x8 __attribute__((ext_vector_type(8)));
typedef unsigned short u16x4 __attribute__((ext_vector_type(4)));

__device__ __forceinline__ float b2f(u16 u) {
    unsigned int x = ((unsigned int)u) << 16;
    return __builtin_bit_cast(float, x);
}
__device__ __forceinline__ u16 f2b(float f) {          // RNE
    unsigned int x = __builtin_bit_cast(unsigned int, f);
    x += 0x7fffu + ((x >> 16) & 1u);
    return (u16)(x >> 16);
}

// async global->LDS, 16B/lane; LDS dest = wave-uniform base + lane*16
typedef const __attribute__((address_space(1))) unsigned int* gas_u32p;
typedef __attribute__((address_space(3))) unsigned int* las_u32p;
__device__ __forceinline__ void gl_lds16(const u16* g, u16* lds_base) {
    __builtin_amdgcn_global_load_lds((gas_u32p)g, (las_u32p)lds_base, 16, 0, 0);
}

// ---------------------------------------------------------------------------
// x fp32 -> bf16, flat
// ---------------------------------------------------------------------------
__global__ __launch_bounds__(256) void cvt_k(const float* __restrict__ in,
                                             u16* __restrict__ out) {
    size_t i = ((size_t)blockIdx.x * 256 + threadIdx.x) * 8;
    float4 a = *(const float4*)(in + i);
    float4 b = *(const float4*)(in + i + 4);
    *(u16x8*)(out + i) = u16x8{f2b(a.x), f2b(a.y), f2b(a.z), f2b(a.w),
                               f2b(b.x), f2b(b.y), f2b(b.z), f2b(b.w)};
}

// ---------------------------------------------------------------------------
// 4 weight transposes fused: z in {0,1,2}: Wq/Wk/Wv -> WqkvT sections
// (z=0 scaled by cscale); z=3: Wo -> WoT.
// ---------------------------------------------------------------------------
__global__ __launch_bounds__(256) void transpose4_k(
    const float* __restrict__ w0, const float* __restrict__ w1,
    const float* __restrict__ w2, const float* __restrict__ w3,
    u16* __restrict__ oqkv, u16* __restrict__ owo, float scale0) {
    __shared__ u16 t[32][33];
    const int z = blockIdx.z;
    const float* in = (z == 0) ? w0 : (z == 1) ? w1 : (z == 2) ? w2 : w3;
    u16* out = (z < 3) ? oqkv + (size_t)z * D_ * D_ : owo;
    const float sc = (z == 0) ? scale0 : 1.0f;
    const int x0 = blockIdx.x * 32, y0 = blockIdx.y * 32;
    const int tx = threadIdx.x & 31, ty = threadIdx.x >> 5;  // 32 x 8
#pragma unroll
    for (int i = 0; i < 32; i += 8)
        t[ty + i][tx] = f2b(in[(size_t)(y0 + ty + i) * D_ + x0 + tx] * sc);
    __syncthreads();
#pragma unroll
    for (int i = 0; i < 32; i += 8)
        out[(size_t)(x0 + ty + i) * D_ + y0 + tx] = t[tx][ty + i];
}

// ---------------------------------------------------------------------------
// GEMM core (m97 structure, BK=64, XOR-swizzled LDS): C = A @ W + bias.
// MODE 0: fused QKV epilogue (N=3072; col>>10 -> Q bf16 / K bf16 / V->Vt).
// MODE 1: fp32 out [M,N].
// ---------------------------------------------------------------------------
#define BM 128
#define BN 128
#define BK 64

template <int MODE>
__global__ __launch_bounds__(256) void gemm_core(
    const u16* __restrict__ A, const u16* __restrict__ Bt,
    const float* __restrict__ b0, const float* __restrict__ b1,
    const float* __restrict__ b2, float cscale,
    void* __restrict__ O0, void* __restrict__ O1, void* __restrict__ O2,
    int M, int N, int K)
{
    __shared__ __align__(16) u16 As[BM * BK];   // 16 KB
    __shared__ __align__(16) u16 Bs[BN * BK];   // 16 KB

    const int tid  = threadIdx.x;
    const int lane = tid & 63;
    const int wave = tid >> 6;
    const int wr = wave >> 1, wc = wave & 1;
    const int l15 = lane & 15, quad = lane >> 4;
    const int m0 = blockIdx.x * BM, n0 = blockIdx.y * BN;
    const int r8 = lane >> 3;
    const int csw = ((lane & 7) ^ r8) * 8;      // swizzled global chunk

    f32x4 acc[4][4] = {};

    for (int k0 = 0; k0 < K; k0 += BK) {
#pragma unroll
        for (int i = 0; i < 4; ++i) {
            const int row = wave * 32 + i * 8 + r8;
            gl_lds16(A  + (size_t)(m0 + row) * K + k0 + csw,
                     As + (wave * 32 + i * 8) * BK);
            gl_lds16(Bt + (size_t)(n0 + row) * K + k0 + csw,
                     Bs + (wave * 32 + i * 8) * BK);
        }
        __syncthreads();
        bf16x8 af[4][2], bfr[4][2];
#pragma unroll
        for (int t = 0; t < 4; ++t) {
            const u16* ap = As + (wr * 64 + t * 16 + l15) * BK;
            const u16* bp = Bs + (wc * 64 + t * 16 + l15) * BK;
            const int s7 = l15 & 7;
            af[t][0]  = *(const bf16x8*)(ap + ((quad    ) ^ s7) * 8);
            af[t][1]  = *(const bf16x8*)(ap + ((quad + 4) ^ s7) * 8);
            bfr[t][0] = *(const bf16x8*)(bp + ((quad    ) ^ s7) * 8);
            bfr[t][1] = *(const bf16x8*)(bp + ((quad + 4) ^ s7) * 8);
        }
#pragma unroll
        for (int mt = 0; mt < 4; ++mt)
#pragma unroll
            for (int nt = 0; nt < 4; ++nt) {
                acc[mt][nt] = __builtin_amdgcn_mfma_f32_16x16x32_bf16(
                    af[mt][0], bfr[nt][0], acc[mt][nt], 0, 0, 0);
                acc[mt][nt] = __builtin_amdgcn_mfma_f32_16x16x32_bf16(
                    af[mt][1], bfr[nt][1], acc[mt][nt], 0, 0, 0);
            }
        __syncthreads();
    }

#pragma unroll
    for (int nt = 0; nt < 4; ++nt) {
        const int col = n0 + wc * 64 + nt * 16 + l15;
        if constexpr (MODE == 1) {
            const float bv = b0[col];
#pragma unroll
            for (int mt = 0; mt < 4; ++mt) {
                const int rbase = m0 + wr * 64 + mt * 16 + quad * 4;
#pragma unroll
                for (int r2 = 0; r2 < 4; ++r2)
                    ((float*)O0)[(size_t)(rbase + r2) * N + col] =
                        acc[mt][nt][r2] + bv;
            }
        } else {
            const int qidx = col >> 10, ncol = col & (D_ - 1);
            const float bv = (qidx == 0) ? b0[ncol] * cscale
                           : (qidx == 1) ? b1[ncol] : b2[ncol];
#pragma unroll
            for (int mt = 0; mt < 4; ++mt) {
                const int rbase = m0 + wr * 64 + mt * 16 + quad * 4;
                if (qidx == 2) {   // Vt layout [B][H][HD][S]
                    const int bidx = rbase >> 11, s = rbase & (S_ - 1);
                    const int hh = ncol >> 6, hd = ncol & 63;
                    u16x4 pk{f2b(acc[mt][nt][0] + bv), f2b(acc[mt][nt][1] + bv),
                             f2b(acc[mt][nt][2] + bv), f2b(acc[mt][nt][3] + bv)};
                    *(u16x4*)((u16*)O2 +
                        (((size_t)(bidx * H_ + hh)) * HD_ + hd) * S_ + s) = pk;
                } else {
                    u16* dst = (qidx == 0) ? (u16*)O0 : (u16*)O1;
#pragma unroll
                    for (int r2 = 0; r2 < 4; ++r2)
                        dst[(size_t)(rbase + r2) * D_ + ncol] =
                            f2b(acc[mt][nt][r2] + bv);
                }
            }
        }
    }
}

// ---------------------------------------------------------------------------
// Causal flash attention, MFMA, LDS-dbuf K/V staging, shuffle P-transform.
// Q pre-scaled by log2(e)/8. K [B,S,H,HD], Vt [B,H,HD,S].
// Block = q-tile pair {j, 31-j}, j=0..15 -> 1024 blocks (4/CU), 33 passes
// per block (balanced); grid (bh, j) -> XCD = bh%8 (head-local L2).
// P: C-layout -> B-layout entirely in-register: data moves only among the
// 4 lanes sharing l15 -> 16 shfl (ds_bpermute) + 8 selects per pass, no
// scratch aliasing -> passes pipeline freely.
//   dest frag f word m  =  w[2f + (quad>>1)][m&1]
//                          from lane l15 + 32*(quad&1) + 16*(m>>1)
// where w[kt][h] packs keys kt*16+quad*4+2h, +2h+1 (C-layout regs).
// ---------------------------------------------------------------------------
__global__ __launch_bounds__(256, 4) void attn_mfma_k(
    const u16* __restrict__ Qm, const u16* __restrict__ Km,
    const u16* __restrict__ Vtg, u16* __restrict__ Om)
{
    __shared__ __align__(16) u16 Kbuf[2][64 * 64];   // 16 KB
    __shared__ __align__(16) u16 Vbuf[2][64 * 64];   // 16 KB
    __shared__ __align__(16) u16 Ps[4][16 * 64];     //  8 KB (epilogue only)

    const int tid  = threadIdx.x;
    const int lane = tid & 63;
    const int wave = tid >> 6;
    const int l15  = lane & 15;
    const int quad = lane >> 4;
    const int s7   = l15 & 7;
    const int bh = blockIdx.x, b = bh >> 4, h = bh & (H_ - 1);
    const int j  = blockIdx.y;                 // 0..15
    const int dg0 = j, dg1 = 31 - j;

    const u16* Qg = Qm + (size_t)b * S_ * D_ + h * HD_;
    const u16* Kg = Km + (size_t)b * S_ * D_ + h * HD_;
    const u16* Vg = Vtg + ((size_t)(b * H_ + h)) * HD_ * S_;

    bf16x8 qf0[2], qf1[2];
    {
        const u16* qp = Qg + (size_t)(dg0 * 64 + wave * 16 + l15) * D_ + quad * 8;
        qf0[0] = *(const bf16x8*)qp; qf0[1] = *(const bf16x8*)(qp + 32);
        qp = Qg + (size_t)(dg1 * 64 + wave * 16 + l15) * D_ + quad * 8;
        qf1[0] = *(const bf16x8*)qp; qf1[1] = *(const bf16x8*)(qp + 32);
    }

    f32x4 of0[4] = {}, of1[4] = {};
    float lacc0 = 0.f, lacc1 = 0.f;
    const int qloc = wave * 16 + l15;
    const int r8 = lane >> 3;
    const int csw = ((lane & 7) ^ r8) * 8;     // swizzled global chunk
    const int srcA = l15 + ((quad & 1) << 5);  // shuffle source lanes
    const int srcB = srcA + 16;

    auto stage = [&](int t, int bsel) {
        u16* kb = Kbuf[bsel];
        u16* vb = Vbuf[bsel];
#pragma unroll
        for (int i = 0; i < 2; ++i) {
            const int row = wave * 16 + i * 8 + r8;
            gl_lds16(Kg + (size_t)(t * 64 + row) * D_ + csw,
                     kb + (wave * 16 + i * 8) * 64);
            gl_lds16(Vg + (size_t)row * S_ + t * 64 + csw,
                     vb + (wave * 16 + i * 8) * 64);
        }
    };

    auto pass = [&](const bf16x8 (&q)[2], f32x4 (&o)[4], float& la,
                    bool domask, const u16* kb, const u16* vb) {
        // S^T = K.Q^T (K frags read from LDS at point of use)
        f32x4 sf[4];
#pragma unroll
        for (int kt = 0; kt < 4; ++kt) {
            const u16* kp = kb + (kt * 16 + l15) * 64;
            bf16x8 k0 = *(const bf16x8*)(kp + ((quad    ) ^ s7) * 8);
            bf16x8 k1 = *(const bf16x8*)(kp + ((quad + 4) ^ s7) * 8);
            f32x4 a = {};
            a = __builtin_amdgcn_mfma_f32_16x16x32_bf16(k0, q[0], a, 0, 0, 0);
            a = __builtin_amdgcn_mfma_f32_16x16x32_bf16(k1, q[1], a, 0, 0, 0);
            sf[kt] = a;
        }
        // exp2 + pack P into w[kt][h] = keys kt*16+quad*4+{2h,2h+1}
        unsigned int w[4][2];
        float ls = 0.f;
        if (domask) {
#pragma unroll
            for (int kt = 0; kt < 4; ++kt)
#pragma unroll
                for (int hh = 0; hh < 2; ++hh) {
                    float v0 = sf[kt][2 * hh], v1 = sf[kt][2 * hh + 1];
                    if (kt * 16 + quad * 4 + 2 * hh     > qloc) v0 = -INFINITY;
                    if (kt * 16 + quad * 4 + 2 * hh + 1 > qloc) v1 = -INFINITY;
                    float p0 = __builtin_amdgcn_exp2f(v0);
                    float p1 = __builtin_amdgcn_exp2f(v1);
                    ls += p0 + p1;
                    w[kt][hh] = (__builtin_bit_cast(unsigned int, p0) >> 16) |
                                (__builtin_bit_cast(unsigned int, p1) & 0xFFFF0000u);
                }
        } else {
#pragma unroll
            for (int kt = 0; kt < 4; ++kt)
#pragma unroll
                for (int hh = 0; hh < 2; ++hh) {
                    float p0 = __builtin_amdgcn_exp2f(sf[kt][2 * hh]);
                    float p1 = __builtin_amdgcn_exp2f(sf[kt][2 * hh + 1]);
                    ls += p0 + p1;
                    w[kt][hh] = (__builtin_bit_cast(unsigned int, p0) >> 16) |
                                (__builtin_bit_cast(unsigned int, p1) & 0xFFFF0000u);
                }
        }
        la += ls;
        // C-layout -> B-layout via shuffles (no LDS)
        const bool hi = (quad & 2) != 0;
        i32x4 f0, f1;
        {
            int a0, a1;
            a0 = __shfl((int)w[0][0], srcA); a1 = __shfl((int)w[1][0], srcA);
            f0.x = hi ? a1 : a0;
            a0 = __shfl((int)w[0][1], srcA); a1 = __shfl((int)w[1][1], srcA);
            f0.y = hi ? a1 : a0;
            a0 = __shfl((int)w[0][0], srcB); a1 = __shfl((int)w[1][0], srcB);
            f0.z = hi ? a1 : a0;
            a0 = __shfl((int)w[0][1], srcB); a1 = __shfl((int)w[1][1], srcB);
            f0.w = hi ? a1 : a0;
            a0 = __shfl((int)w[2][0], srcA); a1 = __shfl((int)w[3][0], srcA);
            f1.x = hi ? a1 : a0;
            a0 = __shfl((int)w[2][1], srcA); a1 = __shfl((int)w[3][1], srcA);
            f1.y = hi ? a1 : a0;
            a0 = __shfl((int)w[2][0], srcB); a1 = __shfl((int)w[3][0], srcB);
            f1.z = hi ? a1 : a0;
            a0 = __shfl((int)w[2][1], srcB); a1 = __shfl((int)w[3][1], srcB);
            f1.w = hi ? a1 : a0;
        }
        bf16x8 pf0 = __builtin_bit_cast(bf16x8, f0);
        bf16x8 pf1 = __builtin_bit_cast(bf16x8, f1);
        // ctx^T += Vt.P^T (V frags read from LDS at point of use)
#pragma unroll
        for (int dt = 0; dt < 4; ++dt) {
            const u16* vp = vb + (dt * 16 + l15) * 64;
            bf16x8 v0 = *(const bf16x8*)(vp + ((quad    ) ^ s7) * 8);
            bf16x8 v1 = *(const bf16x8*)(vp + ((quad + 4) ^ s7) * 8);
            o[dt] = __builtin_amdgcn_mfma_f32_16x16x32_bf16(v0, pf0, o[dt], 0, 0, 0);
            o[dt] = __builtin_amdgcn_mfma_f32_16x16x32_bf16(v1, pf1, o[dt], 0, 0, 0);
        }
    };

    const int T = 32 - j;
    stage(0, 0);
    for (int t = 0; t < T; ++t) {
        __syncthreads();                       // buf[t&1] ready (vmcnt drain)
        if (t + 1 < T) stage(t + 1, (t + 1) & 1);
        const u16* kb = Kbuf[t & 1];
        const u16* vb = Vbuf[t & 1];
        if (t <= dg0) pass(qf0, of0, lacc0, t == dg0, kb, vb);
        pass(qf1, of1, lacc1, t == dg1, kb, vb);   // runs every iteration
    }

    u16* pw = Ps[wave];
    auto epi = [&](const f32x4 (&o)[4], float la, int dgq) {
        float ls = la;
        ls += __shfl_xor(ls, 16);
        ls += __shfl_xor(ls, 32);
        const float inv = 1.f / ls;
#pragma unroll
        for (int dt = 0; dt < 4; ++dt) {
            const int g = dt * 16 + quad * 4;
            const int pos = ((g >> 3) ^ s7) * 8 + (g & 7);
            *(u16x4*)(pw + l15 * 64 + pos) =
                u16x4{f2b(o[dt][0] * inv), f2b(o[dt][1] * inv),
                      f2b(o[dt][2] * inv), f2b(o[dt][3] * inv)};
        }
        const int r  = lane >> 2;
        const int cp = lane & 3;
        u16x8 o0 = *(const u16x8*)(pw + r * 64 + ((2 * cp    ) ^ (r & 7)) * 8);
        u16x8 o1 = *(const u16x8*)(pw + r * 64 + ((2 * cp + 1) ^ (r & 7)) * 8);
        u16* op = Om + ((size_t)(b * S_ + dgq * 64 + wave * 16 + r)) * D_ + h * 64 + cp * 16;
        *(u16x8*)op = o0;
        *(u16x8*)(op + 8) = o1;
    };
    epi(of0, lacc0, dg0);
    epi(of1, lacc1, dg1);
}

// ---------------------------------------------------------------------------
extern "C" void kernel_launch(void* const* d_in, const int* in_sizes, int n_in,
                              void* d_out, int out_size, void* d_ws, size_t ws_size,
                              hipStream_t stream)
{
    (void)in_sizes; (void)n_in; (void)out_size; (void)ws_size;
    const float* x  = (const float*)d_in[0];
    const float* Wq = (const float*)d_in[1];
    const float* bq = (const float*)d_in[2];
    const float* Wk = (const float*)d_in[3];
    const float* bk = (const float*)d_in[4];
    const float* Wv = (const float*)d_in[5];
    const float* bv = (const float*)d_in[6];
    const float* Wo = (const float*)d_in[7];
    const float* bo = (const float*)d_in[8];

    const float cscale = 0.18033688011112042f;  // log2(e)/sqrt(64)

    u16* ws = (u16*)d_ws;
    const size_t MD = (size_t)M_ * D_;
    const size_t DD = (size_t)D_ * D_;
    u16* xb    = ws;            // bf16 [M, D]
    u16* Qb    = xb + MD;       // bf16 [B,S,H,HD], pre-scaled
    u16* Kb    = Qb + MD;       // bf16 [B,S,H,HD]
    u16* Vtb   = Kb + MD;       // bf16 [B,H,HD,S]
    u16* Cb    = Vtb + MD;      // ctx bf16 [M, D]
    u16* WqkvT = Cb + MD;       // bf16 [3072, 1024] (Q section pre-scaled)
    u16* WoT   = WqkvT + 3 * DD;

    cvt_k<<<M_ * D_ / 2048, 256, 0, stream>>>(x, xb);

    transpose4_k<<<dim3(D_ / 32, D_ / 32, 4), 256, 0, stream>>>(
        Wq, Wk, Wv, Wo, WqkvT, WoT, cscale);

    gemm_core<0><<<dim3(M_ / BM, N3_ / BN), 256, 0, stream>>>(
        xb, WqkvT, bq, bk, bv, cscale, Qb, Kb, Vtb, M_, N3_, D_);

    attn_mfma_k<<<dim3(B_ * H_, 16), 256, 0, stream>>>(Qb, Kb, Vtb, Cb);

    gemm_core<1><<<dim3(M_ / BM, D_ / BN), 256, 0, stream>>>(
        Cb, WoT, bo, nullptr, nullptr, 1.0f, d_out, nullptr, nullptr, M_, D_, D_);
}